// Round 1
// baseline (346.355 us; speedup 1.0000x reference)
//
#include <hip/hip_runtime.h>
#include <math.h>

#define NTOK (16 * 8192)   // 131072 tokens
#define H    256
#define E    32
#define SEQ  8192
#define BSZ  16
#define T    2             // tokens per thread (acc[32][2]=64 VGPR -- fits registers, no spill)

// ---------------- zero the workspace accumulators ----------------
__global__ __launch_bounds__(256) void zero_ws_kernel(float* ws) {
    int i = blockIdx.x * 256 + threadIdx.x;
    if (i < BSZ * E * 2) ws[i] = 0.0f;
}

// ---------------- main gate kernel ----------------
// 256 threads = 4 waves sharing one 32KB w-LDS copy. Wave = 32 token-columns x
// 2 h-halves; each thread: T=2 tokens, 128 of 256 h. acc[32][2] in REGISTERS.
// CRITICAL: no runtime indexing of acc anywhere (previous version's
// `#pragma unroll 1` aux loop forced acc into scratch: 92MB HBM writes, 135us).
// Halves combined via shfl_xor(32); each lane finalizes exactly 1 token.
__global__ __launch_bounds__(256, 2) void gate_kernel(
    const float* __restrict__ x, const float* __restrict__ w,
    float* __restrict__ out, float* __restrict__ ws_cnt, float* __restrict__ ws_sum)
{
    __shared__ float w_lds[E * H];   // 32 KB, [e][h]

    const int tid = threadIdx.x;

    // ---- stage w into LDS (coalesced float4: 8 per thread) ----
    {
        float4*       wl = (float4*)w_lds;
        const float4* wg = (const float4*)w;
#pragma unroll
        for (int i = 0; i < (E * H / 4) / 256; ++i)
            wl[tid + 256 * i] = wg[tid + 256 * i];
    }
    __syncthreads();

    const int lane = tid & 63;
    const int col  = lane & 31;       // token column
    const int half = lane >> 5;       // h-half: 0 -> h[0:128), 1 -> h[128:256)
    const int wavebase = blockIdx.x * 256 + (tid >> 6) * 64;   // 64 tokens/wave
    const int tok0 = wavebase + col * T;

    const float* xbase = x + (size_t)tok0 * H + half * 128;
    const float* wbase = w_lds + half * 128;

    float acc[E][T];
#pragma unroll
    for (int e = 0; e < E; ++e)
#pragma unroll
        for (int t = 0; t < T; ++t) acc[e][t] = 0.0f;

    // ---- main loop over my 128-h half, 8 h per step (2 float4 per token) ----
    // 4 float4 prefetched per thread = 4KB/wave in flight (latency hiding with
    // only 2 waves/SIMD of available work).
    float4 cur[T][2], nxt[T][2];
#pragma unroll
    for (int t = 0; t < T; ++t)
#pragma unroll
        for (int j = 0; j < 2; ++j)
            cur[t][j] = *(const float4*)(xbase + t * H + 4 * j);

#pragma unroll 1
    for (int hc = 0; hc < 128; hc += 8) {
        const int hn = (hc + 8) & 127;   // wraps on last iter (L1-hot, in-bounds)
#pragma unroll
        for (int t = 0; t < T; ++t)
#pragma unroll
            for (int j = 0; j < 2; ++j)
                nxt[t][j] = *(const float4*)(xbase + t * H + hn + 4 * j);

#pragma unroll
        for (int e = 0; e < E; ++e) {
            // 2-address broadcast read (halves differ) -> conflict-free
            const float4 w0 = *(const float4*)(wbase + e * H + hc);
            const float4 w1 = *(const float4*)(wbase + e * H + hc + 4);
#pragma unroll
            for (int t = 0; t < T; ++t) {
                // explicit fmaf chain: 8 v_fmac (the += product-tree form costs
                // extra mul/add ops since hipcc contracts but won't reassociate)
                float a = acc[e][t];
                a = fmaf(w0.x, cur[t][0].x, a);
                a = fmaf(w0.y, cur[t][0].y, a);
                a = fmaf(w0.z, cur[t][0].z, a);
                a = fmaf(w0.w, cur[t][0].w, a);
                a = fmaf(w1.x, cur[t][1].x, a);
                a = fmaf(w1.y, cur[t][1].y, a);
                a = fmaf(w1.z, cur[t][1].z, a);
                a = fmaf(w1.w, cur[t][1].w, a);
                acc[e][t] = a;
            }
        }
#pragma unroll
        for (int t = 0; t < T; ++t)
#pragma unroll
            for (int j = 0; j < 2; ++j)
                cur[t][j] = nxt[t][j];
    }

    // ---- combine h-halves: both halves end with full logits for both tokens ----
#pragma unroll
    for (int e = 0; e < E; ++e)
#pragma unroll
        for (int t = 0; t < T; ++t)
            acc[e][t] += __shfl_xor(acc[e][t], 32, 64);

    // ---- each lane finalizes 1 token: token = tok0 + half ----
    // Select my slot into acc[e][0] (static cndmask; frees acc[e][1]).
#pragma unroll
    for (int e = 0; e < E; ++e)
        acc[e][0] = half ? acc[e][1] : acc[e][0];

    float m  = acc[0][0];
    int   id = 0;
#pragma unroll
    for (int e = 1; e < E; ++e) {
        if (acc[e][0] > m) { m = acc[e][0]; id = e; }
    }
    float ss = 0.0f;
#pragma unroll
    for (int e = 0; e < E; ++e) {
        const float p = expf(acc[e][0] - m);
        acc[e][0] = p;                 // reuse: acc[e][0] now holds exp(L-m)
        ss += p;
    }
    const float inv = 1.0f / ss;       // softmax score at argmax; SCALING = 1.0
    const int token = tok0 + half;
    out[token]        = (float)id;
    out[NTOK + token] = inv;

    // ---- aux-loss accumulation: per-(batch,expert) count + score sum ----
    const int b = wavebase >> 13;   // /SEQ, wave-uniform (block is 256-token aligned)

#pragma unroll
    for (int e = 0; e < E; ++e) {
        float sc = acc[e][0] * inv;    // softmax score of my token for expert e
#pragma unroll
        for (int off = 32; off > 0; off >>= 1)
            sc += __shfl_xor(sc, off, 64);
        const unsigned long long blt = __ballot(id == e);   // argmax count, no shfl
        if (lane == 0) {
            atomicAdd(&ws_sum[b * E + e], sc);
            const float cn = (float)__popcll(blt);
            if (cn != 0.0f) atomicAdd(&ws_cnt[b * E + e], cn);
        }
    }
}

// ---------------- aux loss reduction ----------------
__global__ __launch_bounds__(256) void aux_kernel(
    const float* __restrict__ ws_cnt, const float* __restrict__ ws_sum,
    float* __restrict__ out)
{
    const int tid = threadIdx.x;
    float p = 0.0f;
    for (int i = tid; i < BSZ * E; i += 256)
        p += ws_cnt[i] * ws_sum[i];

    __shared__ float red[4];
#pragma unroll
    for (int off = 32; off > 0; off >>= 1)
        p += __shfl_xor(p, off, 64);
    if ((tid & 63) == 0) red[tid >> 6] = p;
    __syncthreads();
    if (tid == 0) {
        float t = red[0] + red[1] + red[2] + red[3];
        // aux = sum_be cnt*ssum * alpha / (B * (SEQ/E) * SEQ)
        out[2 * NTOK] = t * (0.001f / (16.0f * 256.0f * 8192.0f));
    }
}

extern "C" void kernel_launch(void* const* d_in, const int* in_sizes, int n_in,
                              void* d_out, int out_size, void* d_ws, size_t ws_size,
                              hipStream_t stream) {
    const float* x = (const float*)d_in[0];
    const float* w = (const float*)d_in[1];
    float* out    = (float*)d_out;
    float* ws     = (float*)d_ws;
    float* ws_cnt = ws;
    float* ws_sum = ws + BSZ * E;

    zero_ws_kernel<<<4, 256, 0, stream>>>(ws);
    gate_kernel<<<NTOK / 256, 256, 0, stream>>>(x, w, out, ws_cnt, ws_sum);
    aux_kernel<<<1, 256, 0, stream>>>(ws_cnt, ws_sum, out);
}

// Round 2
// 261.444 us; speedup vs baseline: 1.3248x; 1.3248x over previous
//
#include <hip/hip_runtime.h>
#include <math.h>

#define NTOK (16 * 8192)   // 131072 tokens
#define H    256
#define E    32
#define SEQ  8192
#define BSZ  16

// Apply macro M to every expert index. Named-scalar accumulators: rounds 0/1
// proved hipcc leaves a `float acc[32][T]` alloca in scratch even with fully
// static indexing (VGPR_Count=60, WRITE_SIZE=556MB of scratch RMW traffic).
// Named scalars are SSA values -- no alloca, promotion guaranteed.
#define FOR_E(M) M(0) M(1) M(2) M(3) M(4) M(5) M(6) M(7) \
                 M(8) M(9) M(10) M(11) M(12) M(13) M(14) M(15) \
                 M(16) M(17) M(18) M(19) M(20) M(21) M(22) M(23) \
                 M(24) M(25) M(26) M(27) M(28) M(29) M(30) M(31)

__device__ __forceinline__ float waveReduceSum(float v) {
#pragma unroll
    for (int off = 32; off > 0; off >>= 1) v += __shfl_xor(v, off, 64);
    return v;
}

// ---------------- zero the workspace accumulators ----------------
__global__ __launch_bounds__(256) void zero_ws_kernel(float* ws) {
    int i = blockIdx.x * 256 + threadIdx.x;
    if (i < BSZ * E * 2) ws[i] = 0.0f;
}

// ---------------- main gate kernel ----------------
// 256 threads = 4 waves sharing one 32KB w-LDS copy. Wave = 32 token-columns x
// 2 h-halves; each thread: 2 tokens (A,B), 128 of 256 h. 64 named scalar
// accumulators in VGPRs. Halves combined via shfl_xor(32); each lane
// finalizes exactly 1 token (tok0 + half).
__global__ __launch_bounds__(256, 2) void gate_kernel(
    const float* __restrict__ x, const float* __restrict__ w,
    float* __restrict__ out, float* __restrict__ ws_cnt, float* __restrict__ ws_sum)
{
    __shared__ float w_lds[E * H];   // 32 KB, [e][h]

    const int tid = threadIdx.x;

    // ---- stage w into LDS (coalesced float4: 8 per thread) ----
    {
        float4*       wl = (float4*)w_lds;
        const float4* wg = (const float4*)w;
#pragma unroll
        for (int i = 0; i < (E * H / 4) / 256; ++i)
            wl[tid + 256 * i] = wg[tid + 256 * i];
    }
    __syncthreads();

    const int lane = tid & 63;
    const int col  = lane & 31;       // token column
    const int half = lane >> 5;       // h-half: 0 -> h[0:128), 1 -> h[128:256)
    const int wavebase = blockIdx.x * 256 + (tid >> 6) * 64;   // 64 tokens/wave
    const int tok0 = wavebase + col * 2;

    const float* xb = x + (size_t)tok0 * H + half * 128;
    const float* wb = w_lds + half * 128;

#define DECL_ACC(e) float aA##e = 0.0f, aB##e = 0.0f;
    FOR_E(DECL_ACC)

    // ---- main loop over my 128-h half, 8 h per step (2 float4 per token) ----
    // Named prefetch regs: 4 float4 in flight/thread = 4KB/wave (latency hiding
    // with 2 waves/SIMD of available work).
    float4 cA0 = *(const float4*)(xb);
    float4 cA1 = *(const float4*)(xb + 4);
    float4 cB0 = *(const float4*)(xb + H);
    float4 cB1 = *(const float4*)(xb + H + 4);

#pragma unroll 1
    for (int hc = 0; hc < 128; hc += 8) {
        const int hn = (hc + 8) & 127;   // wraps on last iter (L1-hot, in-bounds)
        const float4 nA0 = *(const float4*)(xb + hn);
        const float4 nA1 = *(const float4*)(xb + hn + 4);
        const float4 nB0 = *(const float4*)(xb + H + hn);
        const float4 nB1 = *(const float4*)(xb + H + hn + 4);

        // Per expert: 2 LDS float4 broadcast reads (2 addrs/wave: halves differ
        // -> conflict-free) feed 16 v_fmac.
#define FMA_E(e) { \
        const float4 w0 = *(const float4*)(wb + (e) * H + hc); \
        const float4 w1 = *(const float4*)(wb + (e) * H + hc + 4); \
        float ta = aA##e, tb = aB##e; \
        ta = fmaf(w0.x, cA0.x, ta); ta = fmaf(w0.y, cA0.y, ta); \
        ta = fmaf(w0.z, cA0.z, ta); ta = fmaf(w0.w, cA0.w, ta); \
        ta = fmaf(w1.x, cA1.x, ta); ta = fmaf(w1.y, cA1.y, ta); \
        ta = fmaf(w1.z, cA1.z, ta); ta = fmaf(w1.w, cA1.w, ta); \
        tb = fmaf(w0.x, cB0.x, tb); tb = fmaf(w0.y, cB0.y, tb); \
        tb = fmaf(w0.z, cB0.z, tb); tb = fmaf(w0.w, cB0.w, tb); \
        tb = fmaf(w1.x, cB1.x, tb); tb = fmaf(w1.y, cB1.y, tb); \
        tb = fmaf(w1.z, cB1.z, tb); tb = fmaf(w1.w, cB1.w, tb); \
        aA##e = ta; aB##e = tb; }
        FOR_E(FMA_E)

        cA0 = nA0; cA1 = nA1; cB0 = nB0; cB1 = nB1;
    }

    // ---- combine h-halves: both halves end with full logits for both tokens ----
#define RED_E(e) aA##e += __shfl_xor(aA##e, 32, 64); aB##e += __shfl_xor(aB##e, 32, 64);
    FOR_E(RED_E)

    // ---- each lane finalizes 1 token: token = tok0 + half ----
#define SEL_E(e) const float L##e = half ? aB##e : aA##e;
    FOR_E(SEL_E)

    float m  = -3.402823466e+38f;
    int   id = 0;
    // strict > keeps earliest index on ties (matches top_k)
#define AMAX_E(e) if (L##e > m) { m = L##e; id = (e); }
    FOR_E(AMAX_E)

    float ss = 0.0f;
#define EXP_E(e) const float p##e = __expf(L##e - m); ss += p##e;
    FOR_E(EXP_E)

    const float inv = 1.0f / ss;       // softmax score at argmax; SCALING = 1.0
    const int token = tok0 + half;
    out[token]        = (float)id;
    out[NTOK + token] = inv;

    // ---- aux-loss accumulation: per-(batch,expert) count + score sum ----
    const int b = wavebase >> 13;   // /SEQ, wave-uniform (block is 256-token aligned)

#define AUX_E(e) { \
        const float sc = waveReduceSum(p##e * inv); \
        const unsigned long long bl = __ballot(id == (e)); \
        if (lane == 0) { \
            atomicAdd(&ws_sum[b * E + (e)], sc); \
            const float cn = (float)__popcll(bl); \
            if (cn != 0.0f) atomicAdd(&ws_cnt[b * E + (e)], cn); \
        } }
    FOR_E(AUX_E)
}

// ---------------- aux loss reduction ----------------
__global__ __launch_bounds__(256) void aux_kernel(
    const float* __restrict__ ws_cnt, const float* __restrict__ ws_sum,
    float* __restrict__ out)
{
    const int tid = threadIdx.x;
    float p = 0.0f;
    for (int i = tid; i < BSZ * E; i += 256)
        p += ws_cnt[i] * ws_sum[i];

    __shared__ float red[4];
#pragma unroll
    for (int off = 32; off > 0; off >>= 1)
        p += __shfl_xor(p, off, 64);
    if ((tid & 63) == 0) red[tid >> 6] = p;
    __syncthreads();
    if (tid == 0) {
        float t = red[0] + red[1] + red[2] + red[3];
        // aux = sum_be cnt*ssum * alpha / (B * (SEQ/E) * SEQ)
        out[2 * NTOK] = t * (0.001f / (16.0f * 256.0f * 8192.0f));
    }
}

extern "C" void kernel_launch(void* const* d_in, const int* in_sizes, int n_in,
                              void* d_out, int out_size, void* d_ws, size_t ws_size,
                              hipStream_t stream) {
    const float* x = (const float*)d_in[0];
    const float* w = (const float*)d_in[1];
    float* out    = (float*)d_out;
    float* ws     = (float*)d_ws;
    float* ws_cnt = ws;
    float* ws_sum = ws + BSZ * E;

    zero_ws_kernel<<<4, 256, 0, stream>>>(ws);
    gate_kernel<<<NTOK / 256, 256, 0, stream>>>(x, w, out, ws_cnt, ws_sum);
    aux_kernel<<<1, 256, 0, stream>>>(ws_cnt, ws_sum, out);
}